// Round 2
// baseline (209.373 us; speedup 1.0000x reference)
//
#include <hip/hip_runtime.h>

#define HW      147456           // 384*384
#define NC      5
#define NGROUP  1474560          // 4*10*384*384 / 4 (float4 groups)
#define NBLK    1440             // NGROUP / (1440*256) == 4 exactly
#define SMOOTH  1e-5f

// ---------------------------------------------------------------------------
// Pass 1: grid-stride over float4 pixel groups; per-block 15 partial sums
// written NON-atomically to ws[blockIdx*16 + j].  No init kernel needed:
// every slot [0..NBLK*16) is written unconditionally each call.
// j: 0..4 = sum_x[c], 5..9 = inter[c], 10..14 = count[c], 15 = 0 (pad)
// ---------------------------------------------------------------------------
__global__ __launch_bounds__(256) void dice_main(const float* __restrict__ inp,
                                                 const float* __restrict__ tgt,
                                                 float* __restrict__ part) {
    float sumx[NC]  = {0.f, 0.f, 0.f, 0.f, 0.f};
    float inter[NC] = {0.f, 0.f, 0.f, 0.f, 0.f};
    float cnt[NC]   = {0.f, 0.f, 0.f, 0.f, 0.f};

    const int tid    = blockIdx.x * 256 + threadIdx.x;
    const int stride = gridDim.x * 256;

    for (int g = tid; g < NGROUP; g += stride) {
        const int p  = g << 2;            // pixel index == flat target index
        const int nt = p / HW;            // magic-mul division
        const int hw = p - nt * HW;

        const float4 t4 = reinterpret_cast<const float4*>(tgt)[g];
        const int c0 = (t4.x >= 0.25f) + (t4.x >= 0.375f) + (t4.x >= 0.5f) + (t4.x >= 0.625f);
        const int c1 = (t4.y >= 0.25f) + (t4.y >= 0.375f) + (t4.y >= 0.5f) + (t4.y >= 0.625f);
        const int c2 = (t4.z >= 0.25f) + (t4.z >= 0.375f) + (t4.z >= 0.5f) + (t4.z >= 0.625f);
        const int c3 = (t4.w >= 0.25f) + (t4.w >= 0.375f) + (t4.w >= 0.5f) + (t4.w >= 0.625f);

        const float* base = inp + (size_t)nt * (size_t)(NC * HW) + (size_t)hw;
        #pragma unroll
        for (int c = 0; c < NC; ++c) {
            const float4 x4 = *reinterpret_cast<const float4*>(base + (size_t)c * HW);
            sumx[c] += (x4.x + x4.y) + (x4.z + x4.w);
            float iv = 0.f;
            if (c0 == c) iv += x4.x;
            if (c1 == c) iv += x4.y;
            if (c2 == c) iv += x4.z;
            if (c3 == c) iv += x4.w;
            inter[c] += iv;
            cnt[c]   += (float)((c0 == c) + (c1 == c) + (c2 == c) + (c3 == c));
        }
    }

    float v[15];
    #pragma unroll
    for (int c = 0; c < NC; ++c) { v[c] = sumx[c]; v[5 + c] = inter[c]; v[10 + c] = cnt[c]; }

    // wave-64 butterfly reduce
    #pragma unroll
    for (int j = 0; j < 15; ++j) {
        #pragma unroll
        for (int off = 32; off > 0; off >>= 1)
            v[j] += __shfl_down(v[j], off, 64);
    }

    __shared__ float sm[4][15];
    const int lane = threadIdx.x & 63;
    const int wv   = threadIdx.x >> 6;
    if (lane == 0) {
        #pragma unroll
        for (int j = 0; j < 15; ++j) sm[wv][j] = v[j];
    }
    __syncthreads();
    if (threadIdx.x < 16) {
        float s = 0.f;
        if (threadIdx.x < 15)
            s = sm[0][threadIdx.x] + sm[1][threadIdx.x] +
                sm[2][threadIdx.x] + sm[3][threadIdx.x];
        part[blockIdx.x * 16 + threadIdx.x] = s;   // non-atomic, coalesced
    }
}

// ---------------------------------------------------------------------------
// Pass 2: one block reduces NBLK*16 partials and computes the weighted dice.
// ---------------------------------------------------------------------------
__global__ __launch_bounds__(256) void dice_reduce(const float* __restrict__ part,
                                                   const float* __restrict__ w,
                                                   float* __restrict__ out) {
    const int j  = threadIdx.x & 15;   // which accumulator
    const int rg = threadIdx.x >> 4;   // row group 0..15
    float s = 0.f;
    for (int r = rg; r < NBLK; r += 16)
        s += part[r * 16 + j];         // fully coalesced

    __shared__ float sm[16][17];
    __shared__ float tot[16];
    sm[rg][j] = s;
    __syncthreads();
    if (threadIdx.x < 16) {
        float t = 0.f;
        #pragma unroll
        for (int k = 0; k < 16; ++k) t += sm[k][threadIdx.x];
        tot[threadIdx.x] = t;
    }
    __syncthreads();
    if (threadIdx.x == 0) {
        float loss = 0.f;
        #pragma unroll
        for (int c = 0; c < NC; ++c) {
            const float inter = tot[5 + c];
            const float denom = tot[c] + tot[10 + c];
            loss += w[c] * (1.f - (2.f * inter + SMOOTH) / (denom + SMOOTH));
        }
        out[0] = loss;
    }
}

extern "C" void kernel_launch(void* const* d_in, const int* in_sizes, int n_in,
                              void* d_out, int out_size, void* d_ws, size_t ws_size,
                              hipStream_t stream) {
    const float* inp = (const float*)d_in[0];
    const float* tgt = (const float*)d_in[1];
    const float* wgt = (const float*)d_in[2];
    float* out = (float*)d_out;
    float* ws  = (float*)d_ws;

    dice_main<<<NBLK, 256, 0, stream>>>(inp, tgt, ws);
    dice_reduce<<<1, 256, 0, stream>>>(ws, wgt, out);
}